// Round 3
// baseline (1053.217 us; speedup 1.0000x reference)
//
#include <hip/hip_runtime.h>
#include <cstdint>
#include <cstddef>

typedef unsigned short ushort_t;
typedef __attribute__((ext_vector_type(8))) short bf16x8;
typedef __attribute__((ext_vector_type(8))) ushort_t u16x8;
typedef __attribute__((ext_vector_type(4))) float f32x4;

#define B_ROWS 16384
#define K_DIM  1024
#define H_DIM  4096
#define O_DIM  4
#define KP     3072            // packed K: per k, triples (h,h,l) . (h',l',h')
#define NT     96              // KP/32 K-tiles
#define MARGIN 1e-3f
#define FLAG_CAP (1u<<20)

// ws layout (bytes)
#define OFF_XP   ((size_t)0)                 // 16384*3072*2 = 100663296
#define OFF_WP   ((size_t)100663296)         // 4096*3072*2  =  25165824
#define OFF_BITS ((size_t)125829120)         // 16384*128*4  =   8388608
#define OFF_CNT  ((size_t)134217728)         // 128 B
#define OFF_FLG  ((size_t)134217856)         // 1M * 4 B
#define WS_NEED  ((size_t)138412160)

#define GLD16(g, l) __builtin_amdgcn_global_load_lds(                         \
    (const __attribute__((address_space(1))) void*)(g),                       \
    (__attribute__((address_space(3))) void*)(l), 16, 0, 0)

__device__ __forceinline__ void wgbar() {
    __builtin_amdgcn_sched_barrier(0);
    asm volatile("s_barrier" ::: "memory");
    __builtin_amdgcn_sched_barrier(0);
}

__device__ __forceinline__ ushort_t bf16_rtn(float f) {
    uint32_t u = __float_as_uint(f);
    return (ushort_t)((u + 0x7fffu + ((u >> 16) & 1u)) >> 16);
}

// ---------------------------------------------------------------------------
// split: f32 [rows][1024] -> packed bf16 [rows][3072], 8 elems/thread, 16B stores.
// mode 0: (h,h,l)  mode 1: (h,l,h).  Also zeroes *cnt from block 0 (mode 0 call).
// ---------------------------------------------------------------------------
__global__ __launch_bounds__(256) void split3_v(
    const float* __restrict__ in, ushort_t* __restrict__ out, int n8, int mode,
    uint32_t* __restrict__ cnt)
{
    if (cnt != nullptr && blockIdx.x == 0 && threadIdx.x == 0) *cnt = 0u;
    const int stride = gridDim.x * blockDim.x;
    for (int i = blockIdx.x * blockDim.x + threadIdx.x; i < n8; i += stride) {
        const float4 f0 = reinterpret_cast<const float4*>(in)[2 * i];
        const float4 f1 = reinterpret_cast<const float4*>(in)[2 * i + 1];
        const float f[8] = {f0.x, f0.y, f0.z, f0.w, f1.x, f1.y, f1.z, f1.w};
        ushort_t arr[24];
#pragma unroll
        for (int j = 0; j < 8; ++j) {
            const ushort_t h = bf16_rtn(f[j]);
            const float hf = __uint_as_float((uint32_t)h << 16);
            const ushort_t l = bf16_rtn(f[j] - hf);
            if (mode == 0) { arr[3*j] = h; arr[3*j+1] = h; arr[3*j+2] = l; }
            else           { arr[3*j] = h; arr[3*j+1] = l; arr[3*j+2] = h; }
        }
        const int r = i >> 7, c = i & 127;
        ushort_t* op = out + (size_t)r * KP + c * 24;
#pragma unroll
        for (int v = 0; v < 3; ++v)
            reinterpret_cast<u16x8*>(op)[v] = *reinterpret_cast<const u16x8*>(&arr[8 * v]);
    }
}

// ---------------------------------------------------------------------------
// fc1: 256x256 tile, BK=32, 4-deep LDS ring, counted-vmcnt pipeline, 8 waves.
// Epilogue: spike bits + near-boundary flags.
// ---------------------------------------------------------------------------
__global__ __launch_bounds__(512, 2) void fc1_mfma(
    const ushort_t* __restrict__ Xp, const ushort_t* __restrict__ Wp,
    const float* __restrict__ b1, uint32_t* __restrict__ bits,
    uint32_t* __restrict__ cnt, uint32_t* __restrict__ flags)
{
    __shared__ __align__(16) ushort_t As[4][8192];   // 4 bufs x 256 rows x 32 (64 KB)
    __shared__ __align__(16) ushort_t Bs[4][8192];   // 64 KB

    const int tid  = threadIdx.x;
    const int lane = tid & 63;
    const int wv   = tid >> 6;          // 0..7
    const int wm   = wv >> 2;           // 0..1  (M half)
    const int wn   = wv & 3;            // 0..3  (N quarter)
    const int m0   = blockIdx.y * 256;
    const int n0   = blockIdx.x * 256;

    // staging: one gld call covers 128 rows (wave w -> rows w*16+(l>>2)), 16B/lane.
    // LDS dest linear; global source chunk inverse-swizzled: chunk ^= (row>>1)&3.
    const int srow   = (wv << 4) + (lane >> 2);                  // 0..127 within half
    const int schunk = ((lane & 3) ^ ((lane >> 3) & 3)) << 3;    // ushort offset
    const int sldso  = wv << 9;                                  // wv*512 ushorts

    auto stageA = [&](int buf, int tt) {
        const int k0 = tt * 32;
        GLD16(Xp + (size_t)(m0 + srow) * KP + k0 + schunk,        &As[buf][sldso]);
        GLD16(Xp + (size_t)(m0 + 128 + srow) * KP + k0 + schunk,  &As[buf][4096 + sldso]);
    };
    auto stageB = [&](int buf, int tt) {
        const int k0 = tt * 32;
        GLD16(Wp + (size_t)(n0 + srow) * KP + k0 + schunk,        &Bs[buf][sldso]);
        GLD16(Wp + (size_t)(n0 + 128 + srow) * KP + k0 + schunk,  &Bs[buf][4096 + sldso]);
    };

    const int frow = lane & 15;
    const int fkc  = lane >> 4;         // k-chunk 0..3

    auto readA = [&](int buf, int i) -> bf16x8 {
        const int row = (wm << 7) + (i << 4) + frow;
        const int ch  = fkc ^ ((row >> 1) & 3);
        return *reinterpret_cast<const bf16x8*>(&As[buf][(row << 5) + (ch << 3)]);
    };
    auto readB = [&](int buf, int j) -> bf16x8 {
        const int row = (wn << 6) + (j << 4) + frow;
        const int ch  = fkc ^ ((row >> 1) & 3);
        return *reinterpret_cast<const bf16x8*>(&Bs[buf][(row << 5) + (ch << 3)]);
    };

    f32x4 acc[8][4];
#pragma unroll
    for (int i = 0; i < 8; ++i)
#pragma unroll
        for (int j = 0; j < 4; ++j)
            acc[i][j] = (f32x4){0.f, 0.f, 0.f, 0.f};

    // prologue: stage tiles 0,1,2 (12 gld); wait until tile 0 landed (8 newest fly)
    stageA(0, 0); stageB(0, 0);
    stageA(1, 1); stageB(1, 1);
    stageA(2, 2); stageB(2, 2);
    asm volatile("s_waitcnt vmcnt(8)" ::: "memory");
    wgbar();

    for (int t = 0; t < NT; ++t) {
        const int cb = t & 3, sb = (t + 3) & 3;
        const bool st = (t + 3) < NT;
        bf16x8 afr[4], bfr[4];

        // ---- phase 0: stage A(t+3) | read B j0-3 + A i0-3 | 16 MFMA ----
        if (st) stageA(sb, t + 3);
#pragma unroll
        for (int j = 0; j < 4; ++j) bfr[j] = readB(cb, j);
#pragma unroll
        for (int i = 0; i < 4; ++i) afr[i] = readA(cb, i);
        wgbar();
        __builtin_amdgcn_s_setprio(1);
#pragma unroll
        for (int i = 0; i < 4; ++i)
#pragma unroll
            for (int j = 0; j < 4; ++j)
                acc[i][j] = __builtin_amdgcn_mfma_f32_16x16x32_bf16(
                    afr[i], bfr[j], acc[i][j], 0, 0, 0);
        __builtin_amdgcn_s_setprio(0);
        wgbar();

        // ---- phase 1: stage B(t+3) | read A i4-7 | vmcnt | 16 MFMA ----
        if (st) stageB(sb, t + 3);
#pragma unroll
        for (int i = 0; i < 4; ++i) afr[i] = readA(cb, 4 + i);
        if (t < NT - 3) { asm volatile("s_waitcnt vmcnt(8)" ::: "memory"); }
        else            { asm volatile("s_waitcnt vmcnt(0)" ::: "memory"); }
        wgbar();
        __builtin_amdgcn_s_setprio(1);
#pragma unroll
        for (int i = 0; i < 4; ++i)
#pragma unroll
            for (int j = 0; j < 4; ++j)
                acc[4 + i][j] = __builtin_amdgcn_mfma_f32_16x16x32_bf16(
                    afr[i], bfr[j], acc[4 + i][j], 0, 0, 0);
        __builtin_amdgcn_s_setprio(0);
        wgbar();
    }

    // ---- epilogue: bits + flags (reuse As as bit buffer: 256 rows x 8 words) ----
    __syncthreads();
    uint32_t* bitbuf = (uint32_t*)&As[0][0];
    for (int q = tid; q < 2048; q += 512) bitbuf[q] = 0u;
    __syncthreads();

    float bcol[4];
#pragma unroll
    for (int j = 0; j < 4; ++j) bcol[j] = b1[n0 + (wn << 6) + (j << 4) + frow];

#pragma unroll
    for (int i = 0; i < 8; ++i) {
#pragma unroll
        for (int j = 0; j < 4; ++j) {
            const int col_l = (wn << 6) + (j << 4) + frow;
#pragma unroll
            for (int r = 0; r < 4; ++r) {
                const int row_l = (wm << 7) + (i << 4) + ((lane >> 4) << 2) + r;
                const float cur = acc[i][j][r] + bcol[j];
                if (cur > 1.0f)
                    atomicOr(&bitbuf[(row_l << 3) + (col_l >> 5)], 1u << (col_l & 31));
                if (fabsf(cur - 1.0f) < MARGIN) {
                    uint32_t ix = atomicAdd(cnt, 1u);
                    if (ix < FLAG_CAP)
                        flags[ix] = ((uint32_t)(m0 + row_l) << 12) | (uint32_t)(n0 + col_l);
                }
            }
        }
    }
    __syncthreads();

    for (int q = tid; q < 2048; q += 512) {
        const int row = q >> 3, wo = q & 7;
        bits[(size_t)(m0 + row) * 128 + (blockIdx.x << 3) + wo] = bitbuf[q];
    }
}

// ---------------------------------------------------------------------------
// refine: exact f64 dot for flagged (row,col); fix the spike bit.
// ---------------------------------------------------------------------------
__global__ __launch_bounds__(256) void refine(
    const float* __restrict__ x, const float* __restrict__ W1,
    const float* __restrict__ b1, const uint32_t* __restrict__ cnt,
    const uint32_t* __restrict__ flags, uint32_t* __restrict__ bits)
{
    const int lane = threadIdx.x & 63;
    const int wave = (blockIdx.x * 256 + threadIdx.x) >> 6;
    const int nw   = (gridDim.x * 256) >> 6;
    uint32_t n = *cnt; if (n > FLAG_CAP) n = FLAG_CAP;

    for (uint32_t f = wave; f < n; f += nw) {
        const uint32_t e = flags[f];
        const int row = e >> 12, col = e & 4095;
        const float4* xr = (const float4*)(x  + (size_t)row * K_DIM);
        const float4* wr = (const float4*)(W1 + (size_t)col * K_DIM);
        double s = 0.0;
#pragma unroll
        for (int i = 0; i < 4; ++i) {
            const float4 xa = xr[lane + i * 64];
            const float4 wa = wr[lane + i * 64];
            s = fma((double)xa.x, (double)wa.x, s);
            s = fma((double)xa.y, (double)wa.y, s);
            s = fma((double)xa.z, (double)wa.z, s);
            s = fma((double)xa.w, (double)wa.w, s);
        }
        for (int off = 32; off; off >>= 1) s += __shfl_down(s, off, 64);
        if (lane == 0) {
            const double cur = s + (double)b1[col];
            uint32_t* word = &bits[(size_t)row * 128 + (col >> 5)];
            const uint32_t mask = 1u << (col & 31);
            if (cur > 1.0) atomicOr(word, mask);
            else           atomicAnd(word, ~mask);
        }
    }
}

// ---------------------------------------------------------------------------
// fc2: one wave per batch row; lane covers 64 hidden units; f64 exact.
// ---------------------------------------------------------------------------
__global__ __launch_bounds__(256) void snn_fc2w(
    const uint32_t* __restrict__ bits, const float* __restrict__ W2,
    const float* __restrict__ b2, float* __restrict__ out)
{
    const int lane = threadIdx.x & 63;
    const int row  = (blockIdx.x << 2) + (threadIdx.x >> 6);
    const uint32_t w0 = bits[(size_t)row * 128 + 2 * lane];
    const uint32_t w1 = bits[(size_t)row * 128 + 2 * lane + 1];
    double acc[4];
#pragma unroll
    for (int o = 0; o < 4; ++o) {
        const float4* wrow = (const float4*)(W2 + (size_t)o * H_DIM + lane * 64);
        double a = 0.0;
#pragma unroll
        for (int q = 0; q < 16; ++q) {
            const float4 v = wrow[q];
            const uint32_t word = (q < 8) ? w0 : w1;
            const int bit = (4 * q) & 31;
            if ((word >> bit)       & 1u) a += (double)v.x;
            if ((word >> (bit + 1)) & 1u) a += (double)v.y;
            if ((word >> (bit + 2)) & 1u) a += (double)v.z;
            if ((word >> (bit + 3)) & 1u) a += (double)v.w;
        }
        acc[o] = a;
    }
#pragma unroll
    for (int off = 32; off; off >>= 1)
#pragma unroll
        for (int o = 0; o < 4; ++o) acc[o] += __shfl_down(acc[o], off, 64);
    if (lane == 0) {
#pragma unroll
        for (int o = 0; o < 4; ++o) {
            const double cur = acc[o] + (double)b2[o];
            out[row * 4 + o] = (float)cur;
            out[B_ROWS * O_DIM + row * 4 + o] = (cur > 1.0) ? 1.0f : 0.0f;
        }
    }
}

// ---------------------------------------------------------------------------
// Fallback exact-f64 fc1 (round-1 kernel) for small ws_size
// ---------------------------------------------------------------------------
#define BM 64
#define BN 64
#define BK 32
__global__ __launch_bounds__(256) void snn_fc1(
    const float* __restrict__ x, const float* __restrict__ W1,
    const float* __restrict__ b1, uint32_t* __restrict__ spk_bits)
{
    __shared__ float As[BK][68];
    __shared__ float Bs[BK][68];
    __shared__ uint32_t bitbuf[BM][BN / 32];

    const int tid = threadIdx.x;
    const int m0 = blockIdx.y * BM;
    const int n0 = blockIdx.x * BN;
    const int rm = tid & 15, cn = tid >> 4;
    const int mf = 4 * rm, nf = 4 * cn;

    double acc[4][4];
#pragma unroll
    for (int i = 0; i < 4; ++i)
#pragma unroll
        for (int j = 0; j < 4; ++j) acc[i][j] = 0.0;

    const int sm = tid >> 3, skq = tid & 7;
    for (int kt = 0; kt < K_DIM / BK; ++kt) {
        const int k0 = kt * BK;
#pragma unroll
        for (int s = 0; s < 2; ++s) {
            const int m = sm + 32 * s;
            const float4 av = *reinterpret_cast<const float4*>(
                x + (size_t)(m0 + m) * K_DIM + k0 + 4 * skq);
            As[4 * skq + 0][m] = av.x; As[4 * skq + 1][m] = av.y;
            As[4 * skq + 2][m] = av.z; As[4 * skq + 3][m] = av.w;
            const float4 bv = *reinterpret_cast<const float4*>(
                W1 + (size_t)(n0 + m) * K_DIM + k0 + 4 * skq);
            Bs[4 * skq + 0][m] = bv.x; Bs[4 * skq + 1][m] = bv.y;
            Bs[4 * skq + 2][m] = bv.z; Bs[4 * skq + 3][m] = bv.w;
        }
        __syncthreads();
#pragma unroll
        for (int k = 0; k < BK; ++k) {
            const float4 af = *reinterpret_cast<const float4*>(&As[k][mf]);
            const float4 bf = *reinterpret_cast<const float4*>(&Bs[k][nf]);
            const double a0 = af.x, a1 = af.y, a2 = af.z, a3 = af.w;
            const double b0 = bf.x, b1v = bf.y, b2v = bf.z, b3 = bf.w;
            acc[0][0] = fma(a0, b0, acc[0][0]);  acc[0][1] = fma(a0, b1v, acc[0][1]);
            acc[0][2] = fma(a0, b2v, acc[0][2]); acc[0][3] = fma(a0, b3, acc[0][3]);
            acc[1][0] = fma(a1, b0, acc[1][0]);  acc[1][1] = fma(a1, b1v, acc[1][1]);
            acc[1][2] = fma(a1, b2v, acc[1][2]); acc[1][3] = fma(a1, b3, acc[1][3]);
            acc[2][0] = fma(a2, b0, acc[2][0]);  acc[2][1] = fma(a2, b1v, acc[2][1]);
            acc[2][2] = fma(a2, b2v, acc[2][2]); acc[2][3] = fma(a2, b3, acc[2][3]);
            acc[3][0] = fma(a3, b0, acc[3][0]);  acc[3][1] = fma(a3, b1v, acc[3][1]);
            acc[3][2] = fma(a3, b2v, acc[3][2]); acc[3][3] = fma(a3, b3, acc[3][3]);
        }
        __syncthreads();
    }

    if (tid < BM * (BN / 32)) bitbuf[tid >> 1][tid & 1] = 0u;
    __syncthreads();
#pragma unroll
    for (int j = 0; j < 4; ++j) {
        const int n = nf + j;
        const double bias = (double)b1[n0 + n];
        const int wd = n >> 5, bit = n & 31;
#pragma unroll
        for (int i = 0; i < 4; ++i) {
            const double cur = acc[i][j] + bias;
            if (cur > 1.0) atomicOr(&bitbuf[mf + i][wd], 1u << bit);
        }
    }
    __syncthreads();
    if (tid < 128) {
        const int r = tid >> 1, wd = tid & 1;
        spk_bits[(size_t)(m0 + r) * (H_DIM / 32) + (n0 >> 5) + wd] = bitbuf[r][wd];
    }
}

// ---------------------------------------------------------------------------
extern "C" void kernel_launch(void* const* d_in, const int* in_sizes, int n_in,
                              void* d_out, int out_size, void* d_ws, size_t ws_size,
                              hipStream_t stream) {
    const float* x  = (const float*)d_in[0];
    const float* W1 = (const float*)d_in[1];
    const float* b1 = (const float*)d_in[2];
    const float* W2 = (const float*)d_in[3];
    const float* b2 = (const float*)d_in[4];
    float* out = (float*)d_out;
    char* ws = (char*)d_ws;

    if (ws_size >= WS_NEED) {
        ushort_t* Xp   = (ushort_t*)(ws + OFF_XP);
        ushort_t* Wp   = (ushort_t*)(ws + OFF_WP);
        uint32_t* bits = (uint32_t*)(ws + OFF_BITS);
        uint32_t* cnt  = (uint32_t*)(ws + OFF_CNT);
        uint32_t* flg  = (uint32_t*)(ws + OFF_FLG);

        split3_v<<<2048, 256, 0, stream>>>(x,  Xp, (B_ROWS * K_DIM) / 8, 0, cnt);
        split3_v<<<2048, 256, 0, stream>>>(W1, Wp, (H_DIM * K_DIM) / 8, 1, nullptr);
        fc1_mfma<<<dim3(H_DIM / 256, B_ROWS / 256), 512, 0, stream>>>(
            Xp, Wp, b1, bits, cnt, flg);
        refine<<<1024, 256, 0, stream>>>(x, W1, b1, cnt, flg, bits);
        snn_fc2w<<<B_ROWS / 4, 256, 0, stream>>>(bits, W2, b2, out);
    } else {
        uint32_t* bits = (uint32_t*)ws;
        dim3 g1(H_DIM / BN, B_ROWS / BM);
        snn_fc1<<<g1, 256, 0, stream>>>(x, W1, b1, bits);
        snn_fc2w<<<B_ROWS / 4, 256, 0, stream>>>(bits, W2, b2, out);
    }
}